// Round 1
// baseline (230.500 us; speedup 1.0000x reference)
//
#include <hip/hip_runtime.h>
#include <hip/hip_bf16.h>

// MRConv: B=4, C=192, N=10000, K=16, OUT=384
// out[b,o,n] = relu( sum_ch W[o,ch]*feat[b,ch,n] + bias[o] )
// feat[b,2c,n] = x[b,c,n]; feat[b,2c+1,n] = max_k( x[b,c,e0[b,n,k]] - x[b,c,e1[b,n,k]] )

#define NB   4
#define NC   192
#define NN   10000
#define NK   16
#define NOUT 384
#define K2C  384            // 2*C
#define NPAD 10112          // 79*128, padded node count for GEMM tiles

typedef short bf16x8 __attribute__((ext_vector_type(8)));  // 8 bf16 = 4 VGPRs
typedef float f32x4  __attribute__((ext_vector_type(4)));

__device__ inline unsigned short f2bf(float f) {
    // round-to-nearest-even f32 -> bf16 (finite inputs)
    unsigned int u = __builtin_bit_cast(unsigned int, f);
    u += ((u >> 16) & 1u) + 0x7FFFu;
    return (unsigned short)(u >> 16);
}
__device__ inline float bf2f(unsigned short h) {
    unsigned int u = ((unsigned int)h) << 16;
    return __builtin_bit_cast(float, u);
}

// ---------------- K1: transpose x[b][c][n] f32 -> xT[b][n][c] bf16 ----------------
// grid: 4 * 157 blocks, 256 thr. b = bid&3 (XCD pinning), 64-node tile per block.
__global__ __launch_bounds__(256) void k_transpose(const float* __restrict__ x,
                                                   unsigned short* __restrict__ xT) {
    __shared__ unsigned short tile[NC * 65];   // 192 x 64 (+1 pad) = 24960 B
    int b  = blockIdx.x & 3;
    int nb = (blockIdx.x >> 2) * 64;
    int t  = threadIdx.x;
    const float* xb = x + (size_t)b * NC * NN;
    for (int i = 0; i < 48; ++i) {             // 192*64/256 = 48
        int idx = i * 256 + t;
        int c  = idx >> 6;
        int nl = idx & 63;
        int n  = nb + nl;
        float v = (n < NN) ? xb[(size_t)c * NN + n] : 0.f;   // coalesced along n
        tile[c * 65 + nl] = f2bf(v);
    }
    __syncthreads();
    unsigned short* xTb = xT + (size_t)b * NN * NC;
    for (int i = 0; i < 48; ++i) {
        int idx = i * 256 + t;
        int nl  = idx / NC;                    // const-div, compiler magic-mul
        int c   = idx - nl * NC;
        int n   = nb + nl;
        if (n < NN) xTb[(size_t)n * NC + c] = tile[c * 65 + nl];  // coalesced along c
    }
}

// ---------------- K1b: W f32 [384][384] -> bf16 (ch contiguous) ----------------
__global__ __launch_bounds__(256) void k_wconv(const float* __restrict__ w,
                                               unsigned short* __restrict__ wbf) {
    int i = blockIdx.x * 256 + threadIdx.x;    // grid 576 covers 147456 exactly
    wbf[i] = f2bf(w[i]);
}

// ---------------- K2: gather + max-relative -> featT[b][n][2c|2c+1] bf16 ----------------
// grid: 4 * 157 blocks, 256 thr (4 waves). wave handles 16 nodes sequentially;
// lane covers channels {lane, lane+64, lane+128}. Gathered rows are 384B contiguous.
__global__ __launch_bounds__(256) void k_gather(const unsigned short* __restrict__ xT,
                                                const int* __restrict__ eidx,
                                                unsigned short* __restrict__ featT) {
    int b    = blockIdx.x & 3;
    int tile = blockIdx.x >> 2;
    int w    = threadIdx.x >> 6;
    int lane = threadIdx.x & 63;
    const unsigned short* xTb = xT + (size_t)b * NN * NC;
    unsigned short* fb = featT + (size_t)b * NPAD * K2C;
    const int* e0 = eidx + (size_t)b * NN * NK;                    // neighbors (x_j)
    const int* e1 = eidx + (size_t)NB * NN * NK + (size_t)b * NN * NK;  // centers (x_i)
    int nbase = tile * 64 + w * 16;
    for (int ni = 0; ni < 16; ++ni) {
        int n = nbase + ni;
        if (n >= NN) break;                    // wave-uniform
        int v = 0;
        if (lane < 32) {
            const int* e = (lane < 16) ? e0 : e1;
            v = e[(size_t)n * NK + (lane & 15)];
        }
        unsigned short xc0 = xTb[(size_t)n * NC + lane];
        unsigned short xc1 = xTb[(size_t)n * NC + 64 + lane];
        unsigned short xc2 = xTb[(size_t)n * NC + 128 + lane];
        float m0 = -INFINITY, m1 = -INFINITY, m2 = -INFINITY;
        for (int k = 0; k < 16; ++k) {
            int jk = __shfl(v, k, 64);
            int ik = __shfl(v, k + 16, 64);
            const unsigned short* rj = xTb + (size_t)jk * NC;
            const unsigned short* ri = xTb + (size_t)ik * NC;
            m0 = fmaxf(m0, bf2f(rj[lane])       - bf2f(ri[lane]));
            m1 = fmaxf(m1, bf2f(rj[64 + lane])  - bf2f(ri[64 + lane]));
            m2 = fmaxf(m2, bf2f(rj[128 + lane]) - bf2f(ri[128 + lane]));
        }
        // interleaved write: featT[n][2c]=x_center, [2c+1]=xjmax -> one packed 4B store
        unsigned int* fout = (unsigned int*)(fb + (size_t)n * K2C);
        fout[lane]        = (unsigned int)xc0 | ((unsigned int)f2bf(m0) << 16);
        fout[64 + lane]   = (unsigned int)xc1 | ((unsigned int)f2bf(m1) << 16);
        fout[128 + lane]  = (unsigned int)xc2 | ((unsigned int)f2bf(m2) << 16);
    }
}

// ---------------- K3: GEMM out[b][o][n] = relu(W @ feat + bias), bf16 MFMA ----------------
// grid: 4 * 3 * 79 = 948 blocks, 256 thr (4 waves, 2x2). Block tile 128(M)x128(N),
// wave tile 64x64 = 4x4 frags of 16x16x32. Operands loaded direct from L2 (no LDS):
// A = Wbf row-major [o][ch], B = featT row-major [n][ch] (i.e. B^T layout).
__global__ __launch_bounds__(256) void k_gemm(const unsigned short* __restrict__ wbf,
                                              const unsigned short* __restrict__ featT,
                                              const float* __restrict__ bias,
                                              float* __restrict__ out) {
    int bid   = blockIdx.x;
    int b     = bid & 3;
    int rest  = bid >> 2;
    int mtile = rest % 3;
    int ntile = rest / 3;
    int wv    = threadIdx.x >> 6;
    int lane  = threadIdx.x & 63;
    int waveM = wv >> 1, waveN = wv & 1;
    int m0 = mtile * 128 + waveM * 64;
    int n0 = ntile * 128 + waveN * 64;
    int row  = lane & 15;
    int quad = lane >> 4;
    const unsigned short* fb   = featT + (size_t)b * NPAD * K2C;
    const unsigned short* aptr = wbf + (size_t)(m0 + row) * K2C + quad * 8;
    const unsigned short* bptr = fb  + (size_t)(n0 + row) * K2C + quad * 8;

    f32x4 acc[4][4];
#pragma unroll
    for (int mi = 0; mi < 4; ++mi)
#pragma unroll
        for (int ni = 0; ni < 4; ++ni)
            acc[mi][ni] = (f32x4){0.f, 0.f, 0.f, 0.f};

    for (int k0 = 0; k0 < K2C; k0 += 32) {
        bf16x8 a[4], bb[4];
#pragma unroll
        for (int i = 0; i < 4; ++i)
            a[i]  = *(const bf16x8*)(aptr + (size_t)i * 16 * K2C + k0);
#pragma unroll
        for (int i = 0; i < 4; ++i)
            bb[i] = *(const bf16x8*)(bptr + (size_t)i * 16 * K2C + k0);
#pragma unroll
        for (int mi = 0; mi < 4; ++mi)
#pragma unroll
            for (int ni = 0; ni < 4; ++ni)
                acc[mi][ni] = __builtin_amdgcn_mfma_f32_16x16x32_bf16(a[mi], bb[ni], acc[mi][ni], 0, 0, 0);
    }

    float* ob = out + (size_t)b * NOUT * NN;
#pragma unroll
    for (int mi = 0; mi < 4; ++mi) {
        int obase = m0 + mi * 16 + quad * 4;
#pragma unroll
        for (int ni = 0; ni < 4; ++ni) {
            int n = n0 + ni * 16 + row;
            if (n < NN) {
#pragma unroll
                for (int r = 0; r < 4; ++r) {
                    int o = obase + r;
                    float val = acc[mi][ni][r] + bias[o];
                    ob[(size_t)o * NN + n] = fmaxf(val, 0.f);
                }
            }
        }
    }
}

extern "C" void kernel_launch(void* const* d_in, const int* in_sizes, int n_in,
                              void* d_out, int out_size, void* d_ws, size_t ws_size,
                              hipStream_t stream) {
    const float* x    = (const float*)d_in[0];   // [4,192,10000,1]
    const int*   eidx = (const int*)d_in[1];     // [2,4,10000,16]
    const float* w    = (const float*)d_in[2];   // [384,384]
    const float* bias = (const float*)d_in[3];   // [384]
    float* out = (float*)d_out;                  // [4,384,10000,1,1]

    // workspace layout (bf16, all 16B-aligned):
    //   xT    [4][10000][192]   = 15,360,000 B
    //   featT [4][10112][384]   = 31,064,064 B
    //   wbf   [384][384]        =    294,912 B     total ~46.7 MB
    unsigned short* xT    = (unsigned short*)d_ws;
    unsigned short* featT = xT + (size_t)NB * NN * NC;
    unsigned short* wbf   = featT + (size_t)NB * NPAD * K2C;

    hipLaunchKernelGGL(k_transpose, dim3(4 * 157), dim3(256), 0, stream, x, xT);
    hipLaunchKernelGGL(k_wconv,     dim3(576),     dim3(256), 0, stream, w, wbf);
    hipLaunchKernelGGL(k_gather,    dim3(4 * 157), dim3(256), 0, stream, xT, eidx, featT);
    hipLaunchKernelGGL(k_gemm,      dim3(948),     dim3(256), 0, stream, wbf, featT, bias, out);
}

// Round 2
// 178.061 us; speedup vs baseline: 1.2945x; 1.2945x over previous
//
#include <hip/hip_runtime.h>
#include <hip/hip_bf16.h>

// MRConv: B=4, C=192, N=10000, K=16, OUT=384
// out[b,o,n] = relu( sum_ch W[o,ch]*feat[b,ch,n] + bias[o] )
// feat[b,2c,n] = x[b,c,n]; feat[b,2c+1,n] = max_k( x[b,c,e0[b,n,k]] - x[b,c,e1[b,n,k]] )

#define NB   4
#define NC   192
#define NN   10000
#define NK   16
#define NOUT 384
#define K2C  384            // 2*C
#define NPAD 10112          // 79*128, padded node count for GEMM tiles

typedef short bf16x8 __attribute__((ext_vector_type(8)));  // 8 bf16 = 4 VGPRs
typedef float f32x4  __attribute__((ext_vector_type(4)));

__device__ inline unsigned short f2bf(float f) {
    unsigned int u = __builtin_bit_cast(unsigned int, f);
    u += ((u >> 16) & 1u) + 0x7FFFu;
    return (unsigned short)(u >> 16);
}
__device__ inline float bflo(unsigned int u) {           // low bf16 of dword -> f32
    return __builtin_bit_cast(float, u << 16);
}
__device__ inline float bfhi(unsigned int u) {           // high bf16 of dword -> f32
    return __builtin_bit_cast(float, u & 0xFFFF0000u);
}

// ---------------- K1: transpose x[b][c][n] f32 -> xT[b][n][c] bf16 ----------------
__global__ __launch_bounds__(256) void k_transpose(const float* __restrict__ x,
                                                   unsigned short* __restrict__ xT) {
    __shared__ unsigned short tile[NC * 65];   // 192 x 64 (+1 pad)
    int b  = blockIdx.x & 3;
    int nb = (blockIdx.x >> 2) * 64;
    int t  = threadIdx.x;
    const float* xb = x + (size_t)b * NC * NN;
    for (int i = 0; i < 48; ++i) {             // 192*64/256 = 48
        int idx = i * 256 + t;
        int c  = idx >> 6;
        int nl = idx & 63;
        int n  = nb + nl;
        float v = (n < NN) ? xb[(size_t)c * NN + n] : 0.f;   // coalesced along n
        tile[c * 65 + nl] = f2bf(v);
    }
    __syncthreads();
    unsigned short* xTb = xT + (size_t)b * NN * NC;
    for (int i = 0; i < 48; ++i) {
        int idx = i * 256 + t;
        int nl  = idx / NC;
        int c   = idx - nl * NC;
        int n   = nb + nl;
        if (n < NN) xTb[(size_t)n * NC + c] = tile[c * 65 + nl];  // coalesced along c
    }
}

// ---------------- K1b: W f32 [384][384] -> bf16 ----------------
__global__ __launch_bounds__(256) void k_wconv(const float* __restrict__ w,
                                               unsigned short* __restrict__ wbf) {
    int i = blockIdx.x * 256 + threadIdx.x;    // grid 576 covers 147456 exactly
    wbf[i] = f2bf(w[i]);
}

// ---------------- K2: gather + max-relative -> featT[b][n][2c|2c+1] bf16 ----------------
// Half-wave (32 lanes) per node; dword (2-ch) loads; rows are 96 dwords.
// grid: 4 * 157 blocks, 256 thr. Each half-wave does 8 nodes.
__global__ __launch_bounds__(256, 6) void k_gather(const unsigned short* __restrict__ xT,
                                                   const int* __restrict__ eidx,
                                                   unsigned short* __restrict__ featT) {
    int b    = blockIdx.x & 3;
    int tile = blockIdx.x >> 2;
    int wv   = threadIdx.x >> 6;
    int lane = threadIdx.x & 63;
    int lam  = lane & 31;                      // lane within half-wave
    int hb   = lane & 32;                      // half-wave base for shfl
    const unsigned int* xr = (const unsigned int*)(xT + (size_t)b * NN * NC); // rows of 96 dwords
    unsigned short* fb = featT + (size_t)b * NPAD * K2C;
    int part = lam >> 4;                       // 0 -> e0 (x_j), 1 -> e1 (x_i)
    const int* ep = eidx + (size_t)part * NB * NN * NK + (size_t)b * NN * NK;

    int nbase = tile * 64 + wv * 16 + (hb ? 8 : 0);

    // hoist all 8 index vectors (independent loads)
    int v[8];
#pragma unroll
    for (int it = 0; it < 8; ++it) {
        int n = nbase + it;
        v[it] = (n < NN) ? ep[(size_t)n * NK + (lam & 15)] : 0;
    }

    for (int it = 0; it < 8; ++it) {
        int n = nbase + it;
        if (n >= NN) break;                    // uniform within half-wave
        const unsigned int* crow = xr + (size_t)n * 96;
        unsigned int c0 = crow[lam], c1 = crow[32 + lam], c2 = crow[64 + lam];
        float m0l = -INFINITY, m0h = -INFINITY;
        float m1l = -INFINITY, m1h = -INFINITY;
        float m2l = -INFINITY, m2h = -INFINITY;
#pragma unroll 4
        for (int k = 0; k < 16; ++k) {
            int j = __shfl(v[it], hb + k, 64);
            int i = __shfl(v[it], hb + 16 + k, 64);
            const unsigned int* rj = xr + (size_t)j * 96;
            const unsigned int* ri = xr + (size_t)i * 96;
            unsigned int j0 = rj[lam], j1 = rj[32 + lam], j2 = rj[64 + lam];
            unsigned int i0 = ri[lam], i1 = ri[32 + lam], i2 = ri[64 + lam];
            m0l = fmaxf(m0l, bflo(j0) - bflo(i0));  m0h = fmaxf(m0h, bfhi(j0) - bfhi(i0));
            m1l = fmaxf(m1l, bflo(j1) - bflo(i1));  m1h = fmaxf(m1h, bfhi(j1) - bfhi(i1));
            m2l = fmaxf(m2l, bflo(j2) - bflo(i2));  m2h = fmaxf(m2h, bfhi(j2) - bfhi(i2));
        }
        // out dword c = x[c] | m[c]<<16 ; lane's c-dword d covers channels {2d, 2d+1}
        uint2* orow = (uint2*)(fb + (size_t)n * K2C);      // 96 uint2 per row
        uint2 o0, o1, o2;
        o0.x = (c0 & 0xFFFFu)  | ((unsigned int)f2bf(m0l) << 16);
        o0.y = (c0 >> 16)      | ((unsigned int)f2bf(m0h) << 16);
        o1.x = (c1 & 0xFFFFu)  | ((unsigned int)f2bf(m1l) << 16);
        o1.y = (c1 >> 16)      | ((unsigned int)f2bf(m1h) << 16);
        o2.x = (c2 & 0xFFFFu)  | ((unsigned int)f2bf(m2l) << 16);
        o2.y = (c2 >> 16)      | ((unsigned int)f2bf(m2h) << 16);
        orow[lam]      = o0;
        orow[32 + lam] = o1;
        orow[64 + lam] = o2;
    }
}

// ---------------- K3: GEMM out[b][o][n] = relu(W @ feat + bias) ----------------
// Block: 384 outs x 64 nodes, 4 waves (each 96x64 = 6x4 frags of 16x16x32).
// featT tile (64 rows x 48 granules x 16B = 48 KB) staged ONCE per block via
// global_load_lds_dwordx4 into a swizzled layout: slot(n,j) = n*48 + (j+3n)%48
// -> B-frag ds_read_b128 hits 2 lanes/bank-group (free). W (A-operand) direct
// from global (L2-resident, 295 KB).
__global__ __launch_bounds__(256, 3) void k_gemm(const unsigned short* __restrict__ wbf,
                                                 const unsigned short* __restrict__ featT,
                                                 const float* __restrict__ bias,
                                                 float* __restrict__ out) {
    __shared__ unsigned short lds[64 * 48 * 8];   // 3072 granules of 16B = 48 KB
    int bid  = blockIdx.x;
    int b    = bid & 3;
    int nt   = bid >> 2;                          // 0..157
    int wv   = threadIdx.x >> 6;
    int lane = threadIdx.x & 63;
    int r    = lane & 15;
    int q    = lane >> 4;

    // ---- stage featT tile: 48 issues of 1 KB, 12 per wave ----
    const unsigned short* fbase = featT + (size_t)b * NPAD * K2C + (size_t)(nt * 64) * K2C;
#pragma unroll
    for (int ii = 0; ii < 12; ++ii) {
        int i = wv * 12 + ii;
        unsigned int g = (unsigned int)(i * 64 + lane);   // dest slot index
        unsigned int n = g / 48u;
        unsigned int p = g - n * 48u;
        int j = (int)p - (int)((3u * n) % 48u);
        if (j < 0) j += 48;
        const unsigned short* src = fbase + (size_t)n * K2C + (size_t)j * 8;
        __builtin_amdgcn_global_load_lds(
            (const __attribute__((address_space(1))) unsigned int*)src,
            (__attribute__((address_space(3))) unsigned int*)&lds[(size_t)i * 512],
            16, 0, 0);
    }

    // ---- A (W) addressing: wave covers rows wv*96 .. wv*96+95 ----
    const unsigned short* aptr = wbf + (size_t)(wv * 96 + r) * K2C + q * 8;

    // B slot bases per ni: n = ni*16 + r, u0 = (q + 3n) % 48
    unsigned int nbase[4], u0[4];
#pragma unroll
    for (int ni = 0; ni < 4; ++ni) {
        unsigned int n = ni * 16 + r;
        nbase[ni] = n * 48u;
        u0[ni] = ((unsigned int)q + 3u * n) % 48u;
    }

    f32x4 acc[6][4];
#pragma unroll
    for (int mi = 0; mi < 6; ++mi)
#pragma unroll
        for (int ni = 0; ni < 4; ++ni)
            acc[mi][ni] = (f32x4){0.f, 0.f, 0.f, 0.f};

    __syncthreads();   // drains global_load_lds (vmcnt(0) before s_barrier)

#pragma unroll 2
    for (int t = 0; t < 12; ++t) {
        bf16x8 a[6], bb[4];
#pragma unroll
        for (int mi = 0; mi < 6; ++mi)
            a[mi] = *(const bf16x8*)(aptr + (size_t)mi * 16 * K2C + t * 32);
#pragma unroll
        for (int ni = 0; ni < 4; ++ni) {
            unsigned int u = u0[ni] + 4u * t;
            if (u >= 48u) u -= 48u;
            bb[ni] = *(const bf16x8*)(lds + (size_t)(nbase[ni] + u) * 8);
        }
#pragma unroll
        for (int mi = 0; mi < 6; ++mi)
#pragma unroll
            for (int ni = 0; ni < 4; ++ni)
                acc[mi][ni] = __builtin_amdgcn_mfma_f32_16x16x32_bf16(a[mi], bb[ni], acc[mi][ni], 0, 0, 0);
    }

    float* ob = out + (size_t)b * NOUT * NN;
#pragma unroll
    for (int mi = 0; mi < 6; ++mi) {
        int obase = wv * 96 + mi * 16 + q * 4;
#pragma unroll
        for (int ni = 0; ni < 4; ++ni) {
            int n = nt * 64 + ni * 16 + r;
            if (n < NN) {
#pragma unroll
                for (int rr = 0; rr < 4; ++rr) {
                    int o = obase + rr;
                    float val = acc[mi][ni][rr] + bias[o];
                    ob[(size_t)o * NN + n] = fmaxf(val, 0.f);
                }
            }
        }
    }
}

extern "C" void kernel_launch(void* const* d_in, const int* in_sizes, int n_in,
                              void* d_out, int out_size, void* d_ws, size_t ws_size,
                              hipStream_t stream) {
    const float* x    = (const float*)d_in[0];   // [4,192,10000,1]
    const int*   eidx = (const int*)d_in[1];     // [2,4,10000,16]
    const float* w    = (const float*)d_in[2];   // [384,384]
    const float* bias = (const float*)d_in[3];   // [384]
    float* out = (float*)d_out;                  // [4,384,10000,1,1]

    // workspace: xT [4][10000][192] bf16 (15.36 MB) | featT [4][10112][384] bf16 (31.06 MB)
    //            wbf [384][384] bf16 (0.29 MB)
    unsigned short* xT    = (unsigned short*)d_ws;
    unsigned short* featT = xT + (size_t)NB * NN * NC;
    unsigned short* wbf   = featT + (size_t)NB * NPAD * K2C;

    hipLaunchKernelGGL(k_transpose, dim3(4 * 157), dim3(256), 0, stream, x, xT);
    hipLaunchKernelGGL(k_wconv,     dim3(576),     dim3(256), 0, stream, w, wbf);
    hipLaunchKernelGGL(k_gather,    dim3(4 * 157), dim3(256), 0, stream, xT, eidx, featT);
    hipLaunchKernelGGL(k_gemm,      dim3(4 * 158), dim3(256), 0, stream, wbf, featT, bias, out);
}